// Round 3
// baseline (285.432 us; speedup 1.0000x reference)
//
#include <hip/hip_runtime.h>
#include <hip/hip_bf16.h>

#define NH 8
#define SCALE2 2.8853900817779268f   // 2*log2(e)
#define LOG2E 1.4426950408889634f

typedef __attribute__((ext_vector_type(8))) short short8;
typedef __attribute__((ext_vector_type(4))) float floatx4;

// split fp32 -> bf16 hi + bf16 lo (v ~= hi + lo, residual ~2^-18 rel)
__device__ __forceinline__ void split2(float v, unsigned short& hi, unsigned short& lo) {
    __hip_bfloat16 h = __hip_bfloat16(v);
    float hf = (float)h;
    __hip_bfloat16 l = __hip_bfloat16(v - hf);
    hi = *(unsigned short*)&h;
    lo = *(unsigned short*)&l;
}

__device__ __forceinline__ float rdlane(float v, int lane) {
    return __int_as_float(__builtin_amdgcn_readlane(__float_as_int(v), lane));
}

__device__ __forceinline__ void cvt8(float4 a, float4 b, short8& hi8, short8& lo8) {
    union { short8 v; unsigned short u[8]; } H, L;
    split2(a.x, H.u[0], L.u[0]);
    split2(a.y, H.u[1], L.u[1]);
    split2(a.z, H.u[2], L.u[2]);
    split2(a.w, H.u[3], L.u[3]);
    split2(b.x, H.u[4], L.u[4]);
    split2(b.y, H.u[5], L.u[5]);
    split2(b.z, H.u[6], L.u[6]);
    split2(b.w, H.u[7], L.u[7]);
    hi8 = H.v; lo8 = L.v;
}

// ===== prep: W[512][512] fp32 -> W^T split bf16 [n][k] (z=0: Wk, z=1: Wo) =====
__global__ __launch_bounds__(256) void prep_transpose(
    const float* __restrict__ Wk, const float* __restrict__ Wo,
    unsigned short* __restrict__ WkTh, unsigned short* __restrict__ WkTl,
    unsigned short* __restrict__ WoTh, unsigned short* __restrict__ WoTl)
{
    __shared__ unsigned short Th[64][72];
    __shared__ unsigned short Tl[64][72];
    const int z = blockIdx.z;
    const float* W = z ? Wo : Wk;
    unsigned short* Oh = z ? WoTh : WkTh;
    unsigned short* Ol = z ? WoTl : WkTl;
    const int k0 = blockIdx.x * 64, n0 = blockIdx.y * 64;
    const int tid = threadIdx.x;
    const int rr = tid >> 4, c4 = (tid & 15) * 4;
    #pragma unroll
    for (int j = 0; j < 4; ++j) {
        const int r = rr + 16 * j;
        float4 v = *(const float4*)&W[(size_t)(k0 + r) * 512 + n0 + c4];
        split2(v.x, Th[c4 + 0][r], Tl[c4 + 0][r]);
        split2(v.y, Th[c4 + 1][r], Tl[c4 + 1][r]);
        split2(v.z, Th[c4 + 2][r], Tl[c4 + 2][r]);
        split2(v.w, Th[c4 + 3][r], Tl[c4 + 3][r]);
    }
    __syncthreads();
    const int nl = tid >> 2, kc = (tid & 3) * 16;
    const size_t ob = (size_t)(n0 + nl) * 512 + k0 + kc;
    *(short8*)&Oh[ob] = *(short8*)&Th[nl][kc];
    *(short8*)&Oh[ob + 8] = *(short8*)&Th[nl][kc + 8];
    *(short8*)&Ol[ob] = *(short8*)&Tl[nl][kc];
    *(short8*)&Ol[ob + 8] = *(short8*)&Tl[nl][kc + 8];
}

// ===== prep: effective weights W_eff^T = (Wsub @ Wh)^T split bf16 =====
// z=0: Wq_eff from Wq,Wq_h; z=1: Wk_eff from Wk,Wk_h
__global__ __launch_bounds__(256) void prep_weff(
    const float* __restrict__ Wq, const float* __restrict__ Wk,
    const float* __restrict__ Wq_h, const float* __restrict__ Wk_h,
    unsigned short* __restrict__ WqeTh, unsigned short* __restrict__ WqeTl,
    unsigned short* __restrict__ WkeTh, unsigned short* __restrict__ WkeTl)
{
    __shared__ float As[64][68];   // [d][k_local]
    __shared__ float Bs[64][68];   // [d][e]
    const int tid = threadIdx.x;
    const int k0 = blockIdx.x * 64, h = blockIdx.y, qk = blockIdx.z;
    const float* W = qk ? Wk : Wq;
    const float* Wh = (qk ? Wk_h : Wq_h) + h * 4096;
    unsigned short* Th = qk ? WkeTh : WqeTh;
    unsigned short* Tl = qk ? WkeTl : WqeTl;

    const int rr = tid >> 4, d4 = (tid & 15) * 4;
    #pragma unroll
    for (int j = 0; j < 4; ++j) {
        const int r = rr + 16 * j;
        float4 v = *(const float4*)&W[(size_t)(k0 + r) * 512 + h * 64 + d4];
        As[d4 + 0][r] = v.x;
        As[d4 + 1][r] = v.y;
        As[d4 + 2][r] = v.z;
        As[d4 + 3][r] = v.w;
        *(float4*)&Bs[r][d4] = *(const float4*)&Wh[r * 64 + d4];
    }
    __syncthreads();
    const int ti = tid >> 4, tj = tid & 15;
    float4 acc[4];
    acc[0] = acc[1] = acc[2] = acc[3] = make_float4(0.f, 0.f, 0.f, 0.f);
    #pragma unroll 8
    for (int d = 0; d < 64; ++d) {
        float4 a4 = *(const float4*)&As[d][4 * ti];
        float4 b4 = *(const float4*)&Bs[d][4 * tj];
        acc[0].x = fmaf(a4.x, b4.x, acc[0].x);
        acc[0].y = fmaf(a4.x, b4.y, acc[0].y);
        acc[0].z = fmaf(a4.x, b4.z, acc[0].z);
        acc[0].w = fmaf(a4.x, b4.w, acc[0].w);
        acc[1].x = fmaf(a4.y, b4.x, acc[1].x);
        acc[1].y = fmaf(a4.y, b4.y, acc[1].y);
        acc[1].z = fmaf(a4.y, b4.z, acc[1].z);
        acc[1].w = fmaf(a4.y, b4.w, acc[1].w);
        acc[2].x = fmaf(a4.z, b4.x, acc[2].x);
        acc[2].y = fmaf(a4.z, b4.y, acc[2].y);
        acc[2].z = fmaf(a4.z, b4.z, acc[2].z);
        acc[2].w = fmaf(a4.z, b4.w, acc[2].w);
        acc[3].x = fmaf(a4.w, b4.x, acc[3].x);
        acc[3].y = fmaf(a4.w, b4.y, acc[3].y);
        acc[3].z = fmaf(a4.w, b4.z, acc[3].z);
        acc[3].w = fmaf(a4.w, b4.w, acc[3].w);
    }
    // E[k=k0+4ti+r][e=4tj+c] -> WeT[(h*64+e)*512 + k], split bf16
    #pragma unroll
    for (int c = 0; c < 4; ++c) {
        union { ushort4 v; unsigned short u[4]; } H, L;
        #pragma unroll
        for (int r = 0; r < 4; ++r) {
            float val = c == 0 ? acc[r].x : c == 1 ? acc[r].y : c == 2 ? acc[r].z : acc[r].w;
            split2(val, H.u[r], L.u[r]);
        }
        const size_t ob = (size_t)(h * 64 + 4 * tj + c) * 512 + k0 + 4 * ti;
        *(ushort4*)&Th[ob] = H.v;
        *(ushort4*)&Tl[ob] = L.v;
    }
}

// ===== prep: effective biases bqe = bq@Wq_h ; bke = bk@Wk_h + b_h =====
__global__ __launch_bounds__(512) void prep_bias(
    const float* __restrict__ bq, const float* __restrict__ bk,
    const float* __restrict__ Wq_h, const float* __restrict__ Wk_h,
    const float* __restrict__ b_h,
    float* __restrict__ bqe, float* __restrict__ bke)
{
    const int tid = threadIdx.x;
    const int h = tid >> 6, e = tid & 63;
    float aq = 0.f, ak = 0.f;
    for (int d = 0; d < 64; ++d) {
        aq = fmaf(bq[h * 64 + d], Wq_h[(h * 64 + d) * 64 + e], aq);
        ak = fmaf(bk[h * 64 + d], Wk_h[(h * 64 + d) * 64 + e], ak);
    }
    bqe[tid] = aq;
    bke[tid] = ak + b_h[tid];
}

// ===== MFMA GEMM, bf16 3-term compensated, fused per-mode epilogue =====
// C[1024][512] = A(fp32,[m][k]) @ W^T(bf16 split,[n][k]) + bias[n]
// mode 0: eq  = exp2(SCALE2*C) -> [bh][t][e]        (A=query, W=WqeT, bias=bqe)
// mode 1: ekT = exp2(SCALE2*C) -> [bh][e][s] (T)    (A=key,   W=WkeT, bias=bke)
// mode 2: KhT = bf16(C)        -> [bh][d][s] (T)    (A=key,   W=WkT,  bias=bk)
// mode 3: out = C              -> [m][n]            (A=merged,W=WoT,  bias=bo)
__global__ __launch_bounds__(256, 2) void gemm_split(
    const float* __restrict__ Aq, const float* __restrict__ Akey,
    const unsigned short* __restrict__ W0h, const unsigned short* __restrict__ W0l,
    const unsigned short* __restrict__ W1h, const unsigned short* __restrict__ W1l,
    const unsigned short* __restrict__ W2h, const unsigned short* __restrict__ W2l,
    const float* __restrict__ bias0, const float* __restrict__ bias1,
    const float* __restrict__ bias2,
    float* __restrict__ out0, float* __restrict__ ekT,
    unsigned short* __restrict__ KhT, int mode_ofs)
{
    const int mode = blockIdx.z + mode_ofs;
    const float* A = (mode == 1 || mode == 2) ? Akey : Aq;
    const unsigned short* Wh = (mode == 1) ? W1h : (mode == 2) ? W2h : W0h;
    const unsigned short* Wl = (mode == 1) ? W1l : (mode == 2) ? W2l : W0l;
    const float* bias = (mode == 1) ? bias1 : (mode == 2) ? bias2 : bias0;

    const int tid = threadIdx.x;
    const int wv = tid >> 6, l = tid & 63;
    const int lr = l & 15, lq = l >> 4;
    const int m0 = blockIdx.y * 64 + (wv & 1) * 32;
    const int n0 = blockIdx.x * 64 + (wv >> 1) * 32;

    const size_t aoff0 = (size_t)(m0 + lr) * 512 + lq * 8;
    const size_t aoff1 = aoff0 + (size_t)16 * 512;
    const size_t boff0 = (size_t)(n0 + lr) * 512 + lq * 8;
    const size_t boff1 = boff0 + (size_t)16 * 512;

    floatx4 acc[2][2];
    #pragma unroll
    for (int i = 0; i < 2; ++i)
        #pragma unroll
        for (int j = 0; j < 2; ++j)
            acc[i][j] = (floatx4){0.f, 0.f, 0.f, 0.f};

    #pragma unroll
    for (int k0 = 0; k0 < 512; k0 += 64) {
        short8 ah[2][2], al[2][2], bh8[2][2], bl8[2][2];
        #pragma unroll
        for (int i = 0; i < 2; ++i) {
            #pragma unroll
            for (int c = 0; c < 2; ++c) {
                const float* ap = A + (i ? aoff1 : aoff0) + k0 + c * 32;
                float4 a0 = *(const float4*)ap;
                float4 a1 = *(const float4*)(ap + 4);
                cvt8(a0, a1, ah[i][c], al[i][c]);
                const size_t bo = (i ? boff1 : boff0) + k0 + c * 32;
                bh8[i][c] = *(const short8*)&Wh[bo];
                bl8[i][c] = *(const short8*)&Wl[bo];
            }
        }
        #pragma unroll
        for (int i = 0; i < 2; ++i)
            #pragma unroll
            for (int j = 0; j < 2; ++j)
                #pragma unroll
                for (int c = 0; c < 2; ++c) {
                    acc[i][j] = __builtin_amdgcn_mfma_f32_16x16x32_bf16(ah[i][c], bh8[j][c], acc[i][j], 0, 0, 0);
                    acc[i][j] = __builtin_amdgcn_mfma_f32_16x16x32_bf16(ah[i][c], bl8[j][c], acc[i][j], 0, 0, 0);
                    acc[i][j] = __builtin_amdgcn_mfma_f32_16x16x32_bf16(al[i][c], bh8[j][c], acc[i][j], 0, 0, 0);
                }
    }

    #pragma unroll
    for (int i = 0; i < 2; ++i) {
        #pragma unroll
        for (int j = 0; j < 2; ++j) {
            const int n = n0 + j * 16 + lr;
            const float bv = bias[n];
            #pragma unroll
            for (int r = 0; r < 4; ++r) {
                const int m = m0 + i * 16 + lq * 4 + r;
                float v = acc[i][j][r] + bv;
                if (mode == 0) {
                    v = __builtin_amdgcn_exp2f(SCALE2 * v);
                    out0[(size_t)((m >> 9) * 8 + (n >> 6)) * 32768 + (size_t)(m & 511) * 64 + (n & 63)] = v;
                } else if (mode == 1) {
                    v = __builtin_amdgcn_exp2f(SCALE2 * v);
                    ekT[((size_t)((m >> 9) * 8 + (n >> 6)) * 64 + (n & 63)) * 512 + (m & 511)] = v;
                } else if (mode == 2) {
                    __hip_bfloat16 hb(v);
                    KhT[((size_t)((m >> 9) * 8 + (n >> 6)) * 64 + (n & 63)) * 512 + (m & 511)] = *(unsigned short*)&hb;
                } else {
                    out0[(size_t)m * 512 + n] = v;
                }
            }
        }
    }
}

// ===== additive-attention core: readlane-broadcast score + MFMA P@K =====
__global__ __launch_bounds__(512, 4) void attn_v3(
    const float* __restrict__ eq, const float* __restrict__ ekT,
    const unsigned short* __restrict__ KhT, const float* __restrict__ va_h,
    float* __restrict__ merged)
{
    __shared__ __hip_bfloat16 pA[16][520];
    __shared__ float wsum[16][8];

    const int tid = threadIdx.x;
    const int w = tid >> 6, l = tid & 63;
    const int t0 = blockIdx.x * 16, h = blockIdx.y, b = blockIdx.z;
    const int bh_i = b * NH + h;

    const float* eq_p = eq + (size_t)bh_i * 32768 + (size_t)t0 * 64;
    const float* ekT_p = ekT + (size_t)bh_i * 32768 + tid;   // this thread's s
    const float* va_p = va_h + h * 64;

    // preload full 16x64 eq tile: lane l holds flat[l*16 .. l*16+15]
    float4 eqv[4];
    #pragma unroll
    for (int j = 0; j < 4; ++j) eqv[j] = *(const float4*)&eq_p[l * 16 + 4 * j];
    // va (negated, scaled): lanes 0..15 hold all 64
    float4 va4 = *(const float4*)&va_p[(l & 15) * 4];
    va4.x *= -2.0f; va4.y *= -2.0f; va4.z *= -2.0f; va4.w *= -2.0f;
    // preload this thread's full ek column (64 values)
    float ekv[64];
    #pragma unroll
    for (int j = 0; j < 64; ++j) ekv[j] = ekT_p[(size_t)j * 512];

    float acc[16];
    #pragma unroll
    for (int t = 0; t < 16; ++t) acc[t] = 0.f;

    #pragma unroll
    for (int e0 = 0; e0 < 64; e0 += 16) {
        float nva[16];
        #pragma unroll
        for (int j = 0; j < 16; ++j) {
            const int e = e0 + j;
            float c = (j & 3) == 0 ? va4.x : (j & 3) == 1 ? va4.y : (j & 3) == 2 ? va4.z : va4.w;
            nva[j] = rdlane(c, e >> 2);
        }
        #pragma unroll
        for (int t = 0; t < 16; ++t) {
            const int lt = 4 * t + (e0 >> 4);
            float a = acc[t];
            #pragma unroll
            for (int j = 0; j < 16; ++j) {
                const int q = j >> 2, s3 = j & 3;
                float comp = s3 == 0 ? eqv[q].x : s3 == 1 ? eqv[q].y : s3 == 2 ? eqv[q].z : eqv[q].w;
                float eqs = rdlane(comp, lt);
                a = fmaf(nva[j], __builtin_amdgcn_rcpf(fmaf(eqs, ekv[e0 + j], 1.0f)), a);
            }
            acc[t] = a;
        }
    }

    // softmax denominator (scores bounded ~|2*sum|va|| -> no max-subtract)
    float ev[16];
    #pragma unroll
    for (int t = 0; t < 16; ++t) {
        float s = __builtin_amdgcn_exp2f(acc[t] * LOG2E);
        ev[t] = s;
        #pragma unroll
        for (int off = 32; off > 0; off >>= 1) s += __shfl_xor(s, off, 64);
        if (l == 0) wsum[t][w] = s;
    }
    __syncthreads();
    #pragma unroll
    for (int t = 0; t < 16; ++t) {
        float4 s0 = *(float4*)&wsum[t][0];
        float4 s1 = *(float4*)&wsum[t][4];
        float inv = 1.0f / (((s0.x + s0.y) + (s0.z + s0.w)) + ((s1.x + s1.y) + (s1.z + s1.w)));
        pA[t][tid] = __hip_bfloat16(ev[t] * inv);
    }
    __syncthreads();

    // P(16x512) @ K(512x64) via bf16 MFMA; wave w (<4) owns d in [16w,16w+16)
    if (w < 4) {
        const unsigned short* kp = KhT + (size_t)bh_i * 32768
                                   + ((size_t)(w * 16 + (l & 15))) * 512 + (l >> 4) * 8;
        const __hip_bfloat16* ap = &pA[l & 15][(l >> 4) * 8];
        floatx4 oacc = {0.f, 0.f, 0.f, 0.f};
        #pragma unroll
        for (int kt = 0; kt < 16; ++kt) {
            short8 af = *(const short8*)(ap + kt * 32);
            short8 bf = *(const short8*)(kp + kt * 32);
            oacc = __builtin_amdgcn_mfma_f32_16x16x32_bf16(af, bf, oacc, 0, 0, 0);
        }
        const int row = (l >> 4) * 4;
        const int col = w * 16 + (l & 15);
        float* mp = merged + ((size_t)(b * 512 + t0 + row)) * 512 + h * 64 + col;
        #pragma unroll
        for (int r = 0; r < 4; ++r) mp[r * 512] = oacc[r];
    }
}

extern "C" void kernel_launch(void* const* d_in, const int* in_sizes, int n_in,
                              void* d_out, int out_size, void* d_ws, size_t ws_size,
                              hipStream_t stream) {
    (void)in_sizes; (void)n_in; (void)out_size; (void)ws_size;
    const float* query = (const float*)d_in[0];
    const float* key   = (const float*)d_in[1];
    // d_in[2] (value), d_in[7] (Wv), d_in[8] (bv): dead in the reference
    const float* Wq   = (const float*)d_in[3];
    const float* bq   = (const float*)d_in[4];
    const float* Wk   = (const float*)d_in[5];
    const float* bk   = (const float*)d_in[6];
    const float* Wq_h = (const float*)d_in[9];
    const float* Wk_h = (const float*)d_in[10];
    const float* va_h = (const float*)d_in[11];
    const float* b_h  = (const float*)d_in[12];
    const float* Wo   = (const float*)d_in[13];
    const float* bo   = (const float*)d_in[14];
    float* out = (float*)d_out;

    // workspace layout (11.004 MB total)
    float* ws = (float*)d_ws;
    float* eqb     = ws;                  // 524288 f
    float* ekTb    = eqb + 524288;        // 524288 f
    float* mergedb = ekTb + 524288;       // 524288 f
    float* bqe     = mergedb + 524288;    // 512
    float* bke     = bqe + 512;           // 512
    unsigned short* u = (unsigned short*)(bke + 512);
    unsigned short* WqeTh = u;             u += 262144;
    unsigned short* WqeTl = u;             u += 262144;
    unsigned short* WkeTh = u;             u += 262144;
    unsigned short* WkeTl = u;             u += 262144;
    unsigned short* WkTh  = u;             u += 262144;
    unsigned short* WkTl  = u;             u += 262144;
    unsigned short* WoTh  = u;             u += 262144;
    unsigned short* WoTl  = u;             u += 262144;
    unsigned short* KhTb  = u;             u += 524288;

    // --- prep (all read only d_in) ---
    prep_transpose<<<dim3(8, 8, 2), 256, 0, stream>>>(Wk, Wo, WkTh, WkTl, WoTh, WoTl);
    prep_weff<<<dim3(8, 8, 2), 256, 0, stream>>>(Wq, Wk, Wq_h, Wk_h,
                                                 WqeTh, WqeTl, WkeTh, WkeTl);
    prep_bias<<<1, 512, 0, stream>>>(bq, bk, Wq_h, Wk_h, b_h, bqe, bke);
    // --- eq / ekT / KhT in one launch (modes 0,1,2) ---
    gemm_split<<<dim3(8, 16, 3), 256, 0, stream>>>(
        query, key, WqeTh, WqeTl, WkeTh, WkeTl, WkTh, WkTl,
        bqe, bke, bk, eqb, ekTb, KhTb, 0);
    // --- scores -> softmax -> P@K ---
    attn_v3<<<dim3(32, 8, 2), 512, 0, stream>>>(eqb, ekTb, KhTb, va_h, mergedb);
    // --- out = merged@Wo + bo (mode 3) ---
    gemm_split<<<dim3(8, 16, 1), 256, 0, stream>>>(
        mergedb, mergedb, WoTh, WoTl, WoTh, WoTl, WoTh, WoTl,
        bo, bo, bo, out, ekTb, KhTb, 3);
}

// Round 4
// 242.690 us; speedup vs baseline: 1.1761x; 1.1761x over previous
//
#include <hip/hip_runtime.h>
#include <hip/hip_bf16.h>

#define NH 8
#define SCALE2 2.8853900817779268f   // 2*log2(e)
#define LOG2E 1.4426950408889634f

typedef __attribute__((ext_vector_type(8))) short short8;
typedef __attribute__((ext_vector_type(4))) float floatx4;

__device__ __forceinline__ void split2(float v, unsigned short& hi, unsigned short& lo) {
    __hip_bfloat16 h = __hip_bfloat16(v);
    float hf = (float)h;
    __hip_bfloat16 l = __hip_bfloat16(v - hf);
    hi = *(unsigned short*)&h;
    lo = *(unsigned short*)&l;
}
__device__ __forceinline__ unsigned short bf16u(float v) {
    __hip_bfloat16 h = __hip_bfloat16(v);
    return *(unsigned short*)&h;
}
__device__ __forceinline__ float rdlane(float v, int lane) {
    return __int_as_float(__builtin_amdgcn_readlane(__float_as_int(v), lane));
}

// ===================== prep (one launch, 513 blocks) =====================
// blocks [0,128):   WkT / WoT split-bf16 transpose ([n][k])
// blocks [128,256): Wq_eff^T / Wk_eff^T = (Wsub @ Wh)^T split-bf16
// block  256:       effective biases bqe = bq@Wq_h ; bke = bk@Wk_h + b_h
// blocks [257,513): query/key fp32 -> split bf16 hi/lo (row-major [m][k])
__global__ __launch_bounds__(256) void prep_all(
    const float* __restrict__ Wq, const float* __restrict__ Wk,
    const float* __restrict__ Wo,
    const float* __restrict__ Wq_h, const float* __restrict__ Wk_h,
    const float* __restrict__ b_h,
    const float* __restrict__ bq, const float* __restrict__ bk,
    const float* __restrict__ query, const float* __restrict__ key,
    unsigned short* __restrict__ WkTh, unsigned short* __restrict__ WkTl,
    unsigned short* __restrict__ WoTh, unsigned short* __restrict__ WoTl,
    unsigned short* __restrict__ WqeTh, unsigned short* __restrict__ WqeTl,
    unsigned short* __restrict__ WkeTh, unsigned short* __restrict__ WkeTl,
    float* __restrict__ bqe, float* __restrict__ bke,
    unsigned short* __restrict__ qkh, unsigned short* __restrict__ qkl)
{
    __shared__ float smem[2 * 64 * 68];
    const int bid = blockIdx.x;
    const int tid = threadIdx.x;

    if (bid < 128) {
        // ---- transpose+split W (z=0: Wk, z=1: Wo) ----
        unsigned short* Th = (unsigned short*)smem;        // [64][72]
        unsigned short* Tl = Th + 64 * 72;
        const int z = bid >> 6, rem = bid & 63;
        const int k0 = (rem >> 3) * 64, n0 = (rem & 7) * 64;
        const float* W = z ? Wo : Wk;
        unsigned short* Oh = z ? WoTh : WkTh;
        unsigned short* Ol = z ? WoTl : WkTl;
        const int rr = tid >> 4, c4 = (tid & 15) * 4;
        #pragma unroll
        for (int j = 0; j < 4; ++j) {
            const int r = rr + 16 * j;
            float4 v = *(const float4*)&W[(size_t)(k0 + r) * 512 + n0 + c4];
            split2(v.x, Th[(c4 + 0) * 72 + r], Tl[(c4 + 0) * 72 + r]);
            split2(v.y, Th[(c4 + 1) * 72 + r], Tl[(c4 + 1) * 72 + r]);
            split2(v.z, Th[(c4 + 2) * 72 + r], Tl[(c4 + 2) * 72 + r]);
            split2(v.w, Th[(c4 + 3) * 72 + r], Tl[(c4 + 3) * 72 + r]);
        }
        __syncthreads();
        const int nl = tid >> 2, kc = (tid & 3) * 16;
        const size_t ob = (size_t)(n0 + nl) * 512 + k0 + kc;
        *(short8*)&Oh[ob] = *(short8*)&Th[nl * 72 + kc];
        *(short8*)&Oh[ob + 8] = *(short8*)&Th[nl * 72 + kc + 8];
        *(short8*)&Ol[ob] = *(short8*)&Tl[nl * 72 + kc];
        *(short8*)&Ol[ob + 8] = *(short8*)&Tl[nl * 72 + kc + 8];
    } else if (bid < 256) {
        // ---- effective per-head weights ----
        float* As = smem;                 // [64][68]  [d][k_local]
        float* Bs = smem + 64 * 68;       // [64][68]  [d][e]
        const int rem = bid - 128;
        const int qk = rem >> 6, r2 = rem & 63;
        const int k0 = (r2 >> 3) * 64, h = r2 & 7;
        const float* W = qk ? Wk : Wq;
        const float* Wh = (qk ? Wk_h : Wq_h) + h * 4096;
        unsigned short* Th = qk ? WkeTh : WqeTh;
        unsigned short* Tl = qk ? WkeTl : WqeTl;
        const int rr = tid >> 4, d4 = (tid & 15) * 4;
        #pragma unroll
        for (int j = 0; j < 4; ++j) {
            const int r = rr + 16 * j;
            float4 v = *(const float4*)&W[(size_t)(k0 + r) * 512 + h * 64 + d4];
            As[(d4 + 0) * 68 + r] = v.x;
            As[(d4 + 1) * 68 + r] = v.y;
            As[(d4 + 2) * 68 + r] = v.z;
            As[(d4 + 3) * 68 + r] = v.w;
            *(float4*)&Bs[r * 68 + d4] = *(const float4*)&Wh[r * 64 + d4];
        }
        __syncthreads();
        const int ti = tid >> 4, tj = tid & 15;
        float4 acc[4];
        acc[0] = acc[1] = acc[2] = acc[3] = make_float4(0.f, 0.f, 0.f, 0.f);
        #pragma unroll 8
        for (int d = 0; d < 64; ++d) {
            float4 a4 = *(const float4*)&As[d * 68 + 4 * ti];
            float4 b4 = *(const float4*)&Bs[d * 68 + 4 * tj];
            acc[0].x = fmaf(a4.x, b4.x, acc[0].x);
            acc[0].y = fmaf(a4.x, b4.y, acc[0].y);
            acc[0].z = fmaf(a4.x, b4.z, acc[0].z);
            acc[0].w = fmaf(a4.x, b4.w, acc[0].w);
            acc[1].x = fmaf(a4.y, b4.x, acc[1].x);
            acc[1].y = fmaf(a4.y, b4.y, acc[1].y);
            acc[1].z = fmaf(a4.y, b4.z, acc[1].z);
            acc[1].w = fmaf(a4.y, b4.w, acc[1].w);
            acc[2].x = fmaf(a4.z, b4.x, acc[2].x);
            acc[2].y = fmaf(a4.z, b4.y, acc[2].y);
            acc[2].z = fmaf(a4.z, b4.z, acc[2].z);
            acc[2].w = fmaf(a4.z, b4.w, acc[2].w);
            acc[3].x = fmaf(a4.w, b4.x, acc[3].x);
            acc[3].y = fmaf(a4.w, b4.y, acc[3].y);
            acc[3].z = fmaf(a4.w, b4.z, acc[3].z);
            acc[3].w = fmaf(a4.w, b4.w, acc[3].w);
        }
        #pragma unroll
        for (int c = 0; c < 4; ++c) {
            union { ushort4 v; unsigned short u[4]; } H, L;
            #pragma unroll
            for (int r = 0; r < 4; ++r) {
                float val = c == 0 ? acc[r].x : c == 1 ? acc[r].y : c == 2 ? acc[r].z : acc[r].w;
                split2(val, H.u[r], L.u[r]);
            }
            const size_t ob = (size_t)(h * 64 + 4 * tj + c) * 512 + k0 + 4 * ti;
            *(ushort4*)&Th[ob] = H.v;
            *(ushort4*)&Tl[ob] = L.v;
        }
    } else if (bid == 256) {
        // ---- effective biases ----
        int idx = tid;
        #pragma unroll
        for (int it = 0; it < 2; ++it, idx += 256) {
            const int h = idx >> 6, e = idx & 63;
            float aq = 0.f, ak = 0.f;
            for (int d = 0; d < 64; ++d) {
                aq = fmaf(bq[h * 64 + d], Wq_h[(h * 64 + d) * 64 + e], aq);
                ak = fmaf(bk[h * 64 + d], Wk_h[(h * 64 + d) * 64 + e], ak);
            }
            bqe[idx] = aq;
            bke[idx] = ak + b_h[idx];
        }
    } else {
        // ---- split query/key to bf16 hi/lo ----
        const int id2 = bid - 257;              // 0..255
        const int half = id2 >> 7;              // 0: query, 1: key
        const size_t base = (size_t)(id2 & 127) * 4096;
        const float* src = (half ? key : query) + base;
        unsigned short* dh = qkh + half * 524288 + base;
        unsigned short* dl = qkl + half * 524288 + base;
        #pragma unroll
        for (int r = 0; r < 4; ++r) {
            const int idx = tid * 4 + r * 1024;
            float4 v = *(const float4*)&src[idx];
            union { ushort4 v; unsigned short u[4]; } H, L;
            split2(v.x, H.u[0], L.u[0]);
            split2(v.y, H.u[1], L.u[1]);
            split2(v.z, H.u[2], L.u[2]);
            split2(v.w, H.u[3], L.u[3]);
            *(ushort4*)&dh[idx] = H.v;
            *(ushort4*)&dl[idx] = L.v;
        }
    }
}

// ===== MFMA GEMM on pre-split bf16 (3-term compensated), LDS-staged epilogue =====
// C[1024][512] = A @ W^T + bias
// mode 0: eq  = exp2(SCALE2*C) -> [bh][t][e]     (A=query split, W=WqeT, bias=bqe)
// mode 1: ekT = exp2(SCALE2*C) -> [bh][e][s]     (A=key split,   W=WkeT, bias=bke)
// mode 2: KhT = bf16(C)        -> [bh][d][s]     (A=key split,   W=WkT,  bias=bk)
// mode 3: out = C              -> [m][n]         (A=merged split,W=WoT,  bias=bo)
__global__ __launch_bounds__(256, 4) void gemm_bf16(
    const unsigned short* __restrict__ qkh, const unsigned short* __restrict__ qkl,
    const unsigned short* __restrict__ mh, const unsigned short* __restrict__ ml,
    const unsigned short* __restrict__ W0h, const unsigned short* __restrict__ W0l,
    const unsigned short* __restrict__ W1h, const unsigned short* __restrict__ W1l,
    const unsigned short* __restrict__ W2h, const unsigned short* __restrict__ W2l,
    const unsigned short* __restrict__ W3h, const unsigned short* __restrict__ W3l,
    const float* __restrict__ b0, const float* __restrict__ b1,
    const float* __restrict__ b2, const float* __restrict__ b3,
    float* __restrict__ eq, float* __restrict__ ekT,
    unsigned short* __restrict__ KhT, float* __restrict__ out, int mode_ofs)
{
    __shared__ float Ls[64][68];
    const int mode = blockIdx.z + mode_ofs;
    const unsigned short* AH = mode == 3 ? mh : (mode == 0 ? qkh : qkh + 524288);
    const unsigned short* AL = mode == 3 ? ml : (mode == 0 ? qkl : qkl + 524288);
    const unsigned short* WH = mode == 0 ? W0h : mode == 1 ? W1h : mode == 2 ? W2h : W3h;
    const unsigned short* WL = mode == 0 ? W0l : mode == 1 ? W1l : mode == 2 ? W2l : W3l;
    const float* bias = mode == 0 ? b0 : mode == 1 ? b1 : mode == 2 ? b2 : b3;

    const int tid = threadIdx.x;
    const int wv = tid >> 6, l = tid & 63;
    const int lr = l & 15, lq = l >> 4;
    const int M0 = blockIdx.y * 64;
    const int N0 = blockIdx.x * 64;
    const int m0 = M0 + (wv & 1) * 32;
    const int n0 = N0 + (wv >> 1) * 32;

    const size_t a0 = (size_t)(m0 + lr) * 512 + lq * 8;
    const size_t a1 = a0 + (size_t)16 * 512;
    const size_t bo0 = (size_t)(n0 + lr) * 512 + lq * 8;
    const size_t bo1 = bo0 + (size_t)16 * 512;

    floatx4 acc[2][2];
    #pragma unroll
    for (int i = 0; i < 2; ++i)
        #pragma unroll
        for (int j = 0; j < 2; ++j)
            acc[i][j] = (floatx4){0.f, 0.f, 0.f, 0.f};

    for (int k0 = 0; k0 < 512; k0 += 64) {
        short8 ah[2][2], al8[2][2], bh8[2][2], bl8[2][2];
        #pragma unroll
        for (int i = 0; i < 2; ++i)
            #pragma unroll
            for (int c = 0; c < 2; ++c) {
                const size_t ao = (i ? a1 : a0) + k0 + c * 32;
                ah[i][c] = *(const short8*)&AH[ao];
                al8[i][c] = *(const short8*)&AL[ao];
                const size_t bo = (i ? bo1 : bo0) + k0 + c * 32;
                bh8[i][c] = *(const short8*)&WH[bo];
                bl8[i][c] = *(const short8*)&WL[bo];
            }
        #pragma unroll
        for (int i = 0; i < 2; ++i)
            #pragma unroll
            for (int j = 0; j < 2; ++j)
                #pragma unroll
                for (int c = 0; c < 2; ++c) {
                    acc[i][j] = __builtin_amdgcn_mfma_f32_16x16x32_bf16(ah[i][c], bh8[j][c], acc[i][j], 0, 0, 0);
                    acc[i][j] = __builtin_amdgcn_mfma_f32_16x16x32_bf16(ah[i][c], bl8[j][c], acc[i][j], 0, 0, 0);
                    acc[i][j] = __builtin_amdgcn_mfma_f32_16x16x32_bf16(al8[i][c], bh8[j][c], acc[i][j], 0, 0, 0);
                }
    }

    // stage into LDS: modes 0/3 as [m][n]; modes 1/2 as [n][m]
    #pragma unroll
    for (int i = 0; i < 2; ++i)
        #pragma unroll
        for (int j = 0; j < 2; ++j) {
            const int nl_ = (wv >> 1) * 32 + j * 16 + lr;
            const float bv = bias[N0 + nl_];
            #pragma unroll
            for (int r = 0; r < 4; ++r) {
                const int ml_ = (wv & 1) * 32 + i * 16 + lq * 4 + r;
                float v = acc[i][j][r] + bv;
                if (mode <= 1) v = __builtin_amdgcn_exp2f(SCALE2 * v);
                if (mode == 0 || mode == 3) Ls[ml_][nl_] = v;
                else Ls[nl_][ml_] = v;
            }
        }
    __syncthreads();

    const int bh_i = (M0 >> 9) * NH + (N0 >> 6);
    const int tloc = M0 & 511;
    const int row = tid >> 2, c0 = (tid & 3) * 16;
    if (mode == 0) {
        float* dst = eq + (size_t)bh_i * 32768 + (size_t)(tloc + row) * 64;
        #pragma unroll
        for (int c = 0; c < 4; ++c)
            *(float4*)&dst[c0 + 4 * c] = *(float4*)&Ls[row][c0 + 4 * c];
    } else if (mode == 1) {
        float* dst = ekT + ((size_t)bh_i * 64 + row) * 512 + tloc;
        #pragma unroll
        for (int c = 0; c < 4; ++c)
            *(float4*)&dst[c0 + 4 * c] = *(float4*)&Ls[row][c0 + 4 * c];
    } else if (mode == 2) {
        unsigned short* dst = KhT + ((size_t)bh_i * 64 + row) * 512 + tloc + c0;
        union { short8 v; unsigned short u[8]; } o0, o1;
        #pragma unroll
        for (int i = 0; i < 8; ++i) {
            o0.u[i] = bf16u(Ls[row][c0 + i]);
            o1.u[i] = bf16u(Ls[row][c0 + 8 + i]);
        }
        *(short8*)dst = o0.v;
        *(short8*)(dst + 8) = o1.v;
    } else {
        float* dst = out + (size_t)(M0 + row) * 512 + N0;
        #pragma unroll
        for (int c = 0; c < 4; ++c)
            *(float4*)&dst[c0 + 4 * c] = *(float4*)&Ls[row][c0 + 4 * c];
    }
}

// ===== additive-attention core: 8-t tiles, readlane broadcast, MFMA P@K =====
// score'[t,s] = sum_e (-2 va[e]) * rcp(1 + eq[t][e]*ek[e][s])  (softmax-invariant)
// p = softmax; out[t,d] = sum_s p*K  via bf16 MFMA; merged emitted pre-split bf16
__global__ __launch_bounds__(512, 8) void attn_v4(
    const float* __restrict__ eq, const float* __restrict__ ekT,
    const unsigned short* __restrict__ KhT, const float* __restrict__ va_h,
    unsigned short* __restrict__ mh, unsigned short* __restrict__ ml)
{
    __shared__ __hip_bfloat16 pA[16][520];
    __shared__ float wsum[8][8];

    const int tid = threadIdx.x;
    const int w = tid >> 6, l = tid & 63;
    const int t0 = blockIdx.x * 8, h = blockIdx.y, b = blockIdx.z;
    const int bh_i = b * NH + h;

    // eq tile (8x64 = 512 floats) packed: lane l holds flat[l*8 .. l*8+7]
    const float* eq_p = eq + (size_t)bh_i * 32768 + (size_t)t0 * 64;
    float eqf[8];
    {
        float4 v0 = *(const float4*)&eq_p[l * 8];
        float4 v1 = *(const float4*)&eq_p[l * 8 + 4];
        eqf[0] = v0.x; eqf[1] = v0.y; eqf[2] = v0.z; eqf[3] = v0.w;
        eqf[4] = v1.x; eqf[5] = v1.y; eqf[6] = v1.z; eqf[7] = v1.w;
    }
    const float vaf = -2.0f * va_h[h * 64 + l];   // lane l holds va[l]
    const float* ek_p = ekT + (size_t)bh_i * 32768 + tid;   // this thread's s

    float acc[8];
    #pragma unroll
    for (int t = 0; t < 8; ++t) acc[t] = 0.f;

    #pragma unroll
    for (int e0 = 0; e0 < 64; e0 += 8) {
        float ekv[8], nva[8];
        #pragma unroll
        for (int j = 0; j < 8; ++j) ekv[j] = ek_p[(size_t)(e0 + j) * 512];
        #pragma unroll
        for (int j = 0; j < 8; ++j) nva[j] = rdlane(vaf, e0 + j);
        #pragma unroll
        for (int t = 0; t < 8; ++t) {
            const int ln = t * 8 + (e0 >> 3);
            float a = acc[t];
            #pragma unroll
            for (int j = 0; j < 8; ++j)
                a = fmaf(nva[j], __builtin_amdgcn_rcpf(fmaf(rdlane(eqf[j], ln), ekv[j], 1.0f)), a);
            acc[t] = a;
        }
    }

    // softmax over s (scores bounded by 2*sum|va| -> no max-subtract needed)
    float ev[8];
    #pragma unroll
    for (int t = 0; t < 8; ++t) {
        float s = __builtin_amdgcn_exp2f(acc[t] * LOG2E);
        ev[t] = s;
        #pragma unroll
        for (int off = 32; off > 0; off >>= 1) s += __shfl_xor(s, off, 64);
        if (l == 0) wsum[t][w] = s;
    }
    __syncthreads();
    #pragma unroll
    for (int t = 0; t < 8; ++t) {
        float4 s0 = *(float4*)&wsum[t][0];
        float4 s1 = *(float4*)&wsum[t][4];
        float inv = 1.0f / (((s0.x + s0.y) + (s0.z + s0.w)) + ((s1.x + s1.y) + (s1.z + s1.w)));
        pA[t][tid] = __hip_bfloat16(ev[t] * inv);
    }
    // zero-pad rows 8..15 (MFMA A reads 16 rows)
    {
        short8 z = {0, 0, 0, 0, 0, 0, 0, 0};
        *(short8*)&pA[8 + w][(l & 63) * 8] = z;
    }
    __syncthreads();

    // P(16x512, rows 8..15 zero) @ K(512x64); wave w<4 owns d in [16w,16w+16)
    if (w < 4) {
        const unsigned short* kp = KhT + (size_t)bh_i * 32768
                                   + ((size_t)(w * 16 + (l & 15))) * 512 + (l >> 4) * 8;
        const __hip_bfloat16* ap = &pA[l & 15][(l >> 4) * 8];
        floatx4 oacc = {0.f, 0.f, 0.f, 0.f};
        #pragma unroll
        for (int kt = 0; kt < 16; ++kt) {
            short8 af = *(const short8*)(ap + kt * 32);
            short8 bf = *(const short8*)(kp + kt * 32);
            oacc = __builtin_amdgcn_mfma_f32_16x16x32_bf16(af, bf, oacc, 0, 0, 0);
        }
        const int lq = l >> 4;   // t_local base = lq*4 (valid < 8 -> lq < 2)
        if (lq < 2) {
            const int kcol = h * 64 + w * 16 + (l & 15);
            #pragma unroll
            for (int r = 0; r < 4; ++r) {
                const size_t idx = (size_t)(b * 512 + t0 + lq * 4 + r) * 512 + kcol;
                unsigned short hi, lo;
                split2(oacc[r], hi, lo);
                mh[idx] = hi;
                ml[idx] = lo;
            }
        }
    }
}

extern "C" void kernel_launch(void* const* d_in, const int* in_sizes, int n_in,
                              void* d_out, int out_size, void* d_ws, size_t ws_size,
                              hipStream_t stream) {
    (void)in_sizes; (void)n_in; (void)out_size; (void)ws_size;
    const float* query = (const float*)d_in[0];
    const float* key   = (const float*)d_in[1];
    // d_in[2] (value), d_in[7] (Wv), d_in[8] (bv): dead in the reference
    const float* Wq   = (const float*)d_in[3];
    const float* bq   = (const float*)d_in[4];
    const float* Wk   = (const float*)d_in[5];
    const float* bk   = (const float*)d_in[6];
    const float* Wq_h = (const float*)d_in[9];
    const float* Wk_h = (const float*)d_in[10];
    const float* va_h = (const float*)d_in[11];
    const float* b_h  = (const float*)d_in[12];
    const float* Wo   = (const float*)d_in[13];
    const float* bo   = (const float*)d_in[14];
    float* out = (float*)d_out;

    // workspace layout (~13.6 MB)
    float* ws = (float*)d_ws;
    float* eqb  = ws;                    // 524288 f   [bh][t][e]
    float* ekTb = eqb + 524288;          // 524288 f   [bh][e][s]
    float* bqe  = ekTb + 524288;         // 512
    float* bke  = bqe + 512;             // 512
    unsigned short* u = (unsigned short*)(bke + 512);
    unsigned short* qkh = u;   u += 1048576;   // query|key split hi
    unsigned short* qkl = u;   u += 1048576;   // query|key split lo
    unsigned short* WqeTh = u; u += 262144;
    unsigned short* WqeTl = u; u += 262144;
    unsigned short* WkeTh = u; u += 262144;
    unsigned short* WkeTl = u; u += 262144;
    unsigned short* WkTh = u;  u += 262144;
    unsigned short* WkTl = u;  u += 262144;
    unsigned short* WoTh = u;  u += 262144;
    unsigned short* WoTl = u;  u += 262144;
    unsigned short* KhTb = u;  u += 524288;    // [bh][d][s] bf16
    // merged split aliases the query half of qkh/qkl (dead after gemm_in)
    unsigned short* mh = qkh;
    unsigned short* ml = qkl;

    prep_all<<<dim3(513), 256, 0, stream>>>(
        Wq, Wk, Wo, Wq_h, Wk_h, b_h, bq, bk, query, key,
        WkTh, WkTl, WoTh, WoTl, WqeTh, WqeTl, WkeTh, WkeTl, bqe, bke, qkh, qkl);

    // eq / ekT / KhT (modes 0,1,2)
    gemm_bf16<<<dim3(8, 16, 3), 256, 0, stream>>>(
        qkh, qkl, mh, ml,
        WqeTh, WqeTl, WkeTh, WkeTl, WkTh, WkTl, WoTh, WoTl,
        bqe, bke, bk, bo, eqb, ekTb, KhTb, out, 0);

    // scores -> softmax -> P@K -> merged (pre-split bf16)
    attn_v4<<<dim3(64, 8, 2), 512, 0, stream>>>(eqb, ekTb, KhTb, va_h, mh, ml);

    // out = merged@Wo + bo (mode 3)
    gemm_bf16<<<dim3(8, 16, 1), 256, 0, stream>>>(
        qkh, qkl, mh, ml,
        WqeTh, WqeTl, WkeTh, WkeTl, WkTh, WkTl, WoTh, WoTl,
        bqe, bke, bk, bo, eqb, ekTb, KhTb, out, 3);
}

// Round 5
// 203.730 us; speedup vs baseline: 1.4010x; 1.1912x over previous
//
#include <hip/hip_runtime.h>
#include <hip/hip_bf16.h>

#define NH 8
#define SCALE2 2.8853900817779268f     // 2*log2(e)
#define N2LOG2E -2.8853900817779268f   // -2*log2(e)

typedef __attribute__((ext_vector_type(8))) short short8;
typedef __attribute__((ext_vector_type(4))) float floatx4;

__device__ __forceinline__ void split2(float v, unsigned short& hi, unsigned short& lo) {
    __hip_bfloat16 h = __hip_bfloat16(v);
    float hf = (float)h;
    __hip_bfloat16 l = __hip_bfloat16(v - hf);
    hi = *(unsigned short*)&h;
    lo = *(unsigned short*)&l;
}
__device__ __forceinline__ unsigned short bf16u(float v) {
    __hip_bfloat16 h = __hip_bfloat16(v);
    return *(unsigned short*)&h;
}

// ===================== prep (one launch, 513 blocks) =====================
__global__ __launch_bounds__(256) void prep_all(
    const float* __restrict__ Wq, const float* __restrict__ Wk,
    const float* __restrict__ Wo,
    const float* __restrict__ Wq_h, const float* __restrict__ Wk_h,
    const float* __restrict__ b_h,
    const float* __restrict__ bq, const float* __restrict__ bk,
    const float* __restrict__ query, const float* __restrict__ key,
    unsigned short* __restrict__ WkTh, unsigned short* __restrict__ WkTl,
    unsigned short* __restrict__ WoTh, unsigned short* __restrict__ WoTl,
    unsigned short* __restrict__ WqeTh, unsigned short* __restrict__ WqeTl,
    unsigned short* __restrict__ WkeTh, unsigned short* __restrict__ WkeTl,
    float* __restrict__ bqe, float* __restrict__ bke,
    unsigned short* __restrict__ qkh, unsigned short* __restrict__ qkl)
{
    __shared__ float smem[2 * 64 * 68];
    const int bid = blockIdx.x;
    const int tid = threadIdx.x;

    if (bid < 128) {
        // ---- transpose+split W (z=0: Wk, z=1: Wo) -> [n][k] ----
        unsigned short* Th = (unsigned short*)smem;        // [64][72]
        unsigned short* Tl = Th + 64 * 72;
        const int z = bid >> 6, rem = bid & 63;
        const int k0 = (rem >> 3) * 64, n0 = (rem & 7) * 64;
        const float* W = z ? Wo : Wk;
        unsigned short* Oh = z ? WoTh : WkTh;
        unsigned short* Ol = z ? WoTl : WkTl;
        const int rr = tid >> 4, c4 = (tid & 15) * 4;
        #pragma unroll
        for (int j = 0; j < 4; ++j) {
            const int r = rr + 16 * j;
            float4 v = *(const float4*)&W[(size_t)(k0 + r) * 512 + n0 + c4];
            split2(v.x, Th[(c4 + 0) * 72 + r], Tl[(c4 + 0) * 72 + r]);
            split2(v.y, Th[(c4 + 1) * 72 + r], Tl[(c4 + 1) * 72 + r]);
            split2(v.z, Th[(c4 + 2) * 72 + r], Tl[(c4 + 2) * 72 + r]);
            split2(v.w, Th[(c4 + 3) * 72 + r], Tl[(c4 + 3) * 72 + r]);
        }
        __syncthreads();
        const int nl = tid >> 2, kc = (tid & 3) * 16;
        const size_t ob = (size_t)(n0 + nl) * 512 + k0 + kc;
        *(short8*)&Oh[ob] = *(short8*)&Th[nl * 72 + kc];
        *(short8*)&Oh[ob + 8] = *(short8*)&Th[nl * 72 + kc + 8];
        *(short8*)&Ol[ob] = *(short8*)&Tl[nl * 72 + kc];
        *(short8*)&Ol[ob + 8] = *(short8*)&Tl[nl * 72 + kc + 8];
    } else if (bid < 256) {
        // ---- effective per-head weights (Wsub @ Wh)^T split ----
        float* As = smem;                 // [64][68]  [d][k_local]
        float* Bs = smem + 64 * 68;       // [64][68]  [d][e]
        const int rem = bid - 128;
        const int qk = rem >> 6, r2 = rem & 63;
        const int k0 = (r2 >> 3) * 64, h = r2 & 7;
        const float* W = qk ? Wk : Wq;
        const float* Wh = (qk ? Wk_h : Wq_h) + h * 4096;
        unsigned short* Th = qk ? WkeTh : WqeTh;
        unsigned short* Tl = qk ? WkeTl : WqeTl;
        const int rr = tid >> 4, d4 = (tid & 15) * 4;
        #pragma unroll
        for (int j = 0; j < 4; ++j) {
            const int r = rr + 16 * j;
            float4 v = *(const float4*)&W[(size_t)(k0 + r) * 512 + h * 64 + d4];
            As[(d4 + 0) * 68 + r] = v.x;
            As[(d4 + 1) * 68 + r] = v.y;
            As[(d4 + 2) * 68 + r] = v.z;
            As[(d4 + 3) * 68 + r] = v.w;
            *(float4*)&Bs[r * 68 + d4] = *(const float4*)&Wh[r * 64 + d4];
        }
        __syncthreads();
        const int ti = tid >> 4, tj = tid & 15;
        float4 acc[4];
        acc[0] = acc[1] = acc[2] = acc[3] = make_float4(0.f, 0.f, 0.f, 0.f);
        #pragma unroll 8
        for (int d = 0; d < 64; ++d) {
            float4 a4 = *(const float4*)&As[d * 68 + 4 * ti];
            float4 b4 = *(const float4*)&Bs[d * 68 + 4 * tj];
            acc[0].x = fmaf(a4.x, b4.x, acc[0].x);
            acc[0].y = fmaf(a4.x, b4.y, acc[0].y);
            acc[0].z = fmaf(a4.x, b4.z, acc[0].z);
            acc[0].w = fmaf(a4.x, b4.w, acc[0].w);
            acc[1].x = fmaf(a4.y, b4.x, acc[1].x);
            acc[1].y = fmaf(a4.y, b4.y, acc[1].y);
            acc[1].z = fmaf(a4.y, b4.z, acc[1].z);
            acc[1].w = fmaf(a4.y, b4.w, acc[1].w);
            acc[2].x = fmaf(a4.z, b4.x, acc[2].x);
            acc[2].y = fmaf(a4.z, b4.y, acc[2].y);
            acc[2].z = fmaf(a4.z, b4.z, acc[2].z);
            acc[2].w = fmaf(a4.z, b4.w, acc[2].w);
            acc[3].x = fmaf(a4.w, b4.x, acc[3].x);
            acc[3].y = fmaf(a4.w, b4.y, acc[3].y);
            acc[3].z = fmaf(a4.w, b4.z, acc[3].z);
            acc[3].w = fmaf(a4.w, b4.w, acc[3].w);
        }
        #pragma unroll
        for (int c = 0; c < 4; ++c) {
            union { ushort4 v; unsigned short u[4]; } H, L;
            #pragma unroll
            for (int r = 0; r < 4; ++r) {
                float val = c == 0 ? acc[r].x : c == 1 ? acc[r].y : c == 2 ? acc[r].z : acc[r].w;
                split2(val, H.u[r], L.u[r]);
            }
            const size_t ob = (size_t)(h * 64 + 4 * tj + c) * 512 + k0 + 4 * ti;
            *(ushort4*)&Th[ob] = H.v;
            *(ushort4*)&Tl[ob] = L.v;
        }
    } else if (bid == 256) {
        // ---- effective biases ----
        int idx = tid;
        #pragma unroll
        for (int it = 0; it < 2; ++it, idx += 256) {
            const int h = idx >> 6, e = idx & 63;
            float aq = 0.f, ak = 0.f;
            for (int d = 0; d < 64; ++d) {
                aq = fmaf(bq[h * 64 + d], Wq_h[(h * 64 + d) * 64 + e], aq);
                ak = fmaf(bk[h * 64 + d], Wk_h[(h * 64 + d) * 64 + e], ak);
            }
            bqe[idx] = aq;
            bke[idx] = ak + b_h[idx];
        }
    } else {
        // ---- split query/key to bf16 hi/lo ----
        const int id2 = bid - 257;
        const int half = id2 >> 7;
        const size_t base = (size_t)(id2 & 127) * 4096;
        const float* src = (half ? key : query) + base;
        unsigned short* dh = qkh + half * 524288 + base;
        unsigned short* dl = qkl + half * 524288 + base;
        #pragma unroll
        for (int r = 0; r < 4; ++r) {
            const int idx = tid * 4 + r * 1024;
            float4 v = *(const float4*)&src[idx];
            union { ushort4 v; unsigned short u[4]; } H, L;
            split2(v.x, H.u[0], L.u[0]);
            split2(v.y, H.u[1], L.u[1]);
            split2(v.z, H.u[2], L.u[2]);
            split2(v.w, H.u[3], L.u[3]);
            *(ushort4*)&dh[idx] = H.v;
            *(ushort4*)&dl[idx] = L.v;
        }
    }
}

// ===== MFMA GEMM, pre-split bf16 3-term, double-buffered k-chunks of 32 =====
// mode 0: eq  = exp2(SCALE2*C) -> [bh][t][e]
// mode 1: ekR = exp2(SCALE2*C) -> [bh][s][e]   (same addressing as mode 0)
// mode 2: KhT = bf16(C)        -> [bh][d][s]   (transposed)
// mode 3: out = C              -> [m][n]
__global__ __launch_bounds__(256, 4) void gemm_bf16(
    const unsigned short* __restrict__ qkh, const unsigned short* __restrict__ qkl,
    const unsigned short* __restrict__ mh, const unsigned short* __restrict__ ml,
    const unsigned short* __restrict__ W0h, const unsigned short* __restrict__ W0l,
    const unsigned short* __restrict__ W1h, const unsigned short* __restrict__ W1l,
    const unsigned short* __restrict__ W2h, const unsigned short* __restrict__ W2l,
    const unsigned short* __restrict__ W3h, const unsigned short* __restrict__ W3l,
    const float* __restrict__ b0, const float* __restrict__ b1,
    const float* __restrict__ b2, const float* __restrict__ b3,
    float* __restrict__ eq, float* __restrict__ ekR,
    unsigned short* __restrict__ KhT, float* __restrict__ out, int mode_ofs)
{
    __shared__ float Ls[64][68];
    const int mode = blockIdx.z + mode_ofs;
    const unsigned short* AH = mode == 3 ? mh : (mode == 0 ? qkh : qkh + 524288);
    const unsigned short* AL = mode == 3 ? ml : (mode == 0 ? qkl : qkl + 524288);
    const unsigned short* WH = mode == 0 ? W0h : mode == 1 ? W1h : mode == 2 ? W2h : W3h;
    const unsigned short* WL = mode == 0 ? W0l : mode == 1 ? W1l : mode == 2 ? W2l : W3l;
    const float* bias = mode == 0 ? b0 : mode == 1 ? b1 : mode == 2 ? b2 : b3;

    const int tid = threadIdx.x;
    const int wv = tid >> 6, l = tid & 63;
    const int lr = l & 15, lq = l >> 4;
    const int M0 = blockIdx.y * 64;
    const int N0 = blockIdx.x * 64;
    const int m0 = M0 + (wv & 1) * 32;
    const int n0 = N0 + (wv >> 1) * 32;

    const size_t a0 = (size_t)(m0 + lr) * 512 + lq * 8;
    const size_t a1 = a0 + (size_t)16 * 512;
    const size_t b0o = (size_t)(n0 + lr) * 512 + lq * 8;
    const size_t b1o = b0o + (size_t)16 * 512;

    short8 fa[2][2][2], fb[2][2][2];   // [buf][i-strip][hi/lo]
#define LOADC(buf, koff) do { \
        fa[buf][0][0] = *(const short8*)&AH[a0 + (koff)]; \
        fa[buf][0][1] = *(const short8*)&AL[a0 + (koff)]; \
        fa[buf][1][0] = *(const short8*)&AH[a1 + (koff)]; \
        fa[buf][1][1] = *(const short8*)&AL[a1 + (koff)]; \
        fb[buf][0][0] = *(const short8*)&WH[b0o + (koff)]; \
        fb[buf][0][1] = *(const short8*)&WL[b0o + (koff)]; \
        fb[buf][1][0] = *(const short8*)&WH[b1o + (koff)]; \
        fb[buf][1][1] = *(const short8*)&WL[b1o + (koff)]; \
    } while (0)

    floatx4 acc[2][2];
    #pragma unroll
    for (int i = 0; i < 2; ++i)
        #pragma unroll
        for (int j = 0; j < 2; ++j)
            acc[i][j] = (floatx4){0.f, 0.f, 0.f, 0.f};

    LOADC(0, 0);
    #pragma unroll
    for (int c = 0; c < 16; ++c) {
        const int cb = c & 1, nb = cb ^ 1;
        if (c < 15) LOADC(nb, (c + 1) * 32);
        #pragma unroll
        for (int i = 0; i < 2; ++i)
            #pragma unroll
            for (int j = 0; j < 2; ++j) {
                acc[i][j] = __builtin_amdgcn_mfma_f32_16x16x32_bf16(fa[cb][i][0], fb[cb][j][0], acc[i][j], 0, 0, 0);
                acc[i][j] = __builtin_amdgcn_mfma_f32_16x16x32_bf16(fa[cb][i][0], fb[cb][j][1], acc[i][j], 0, 0, 0);
                acc[i][j] = __builtin_amdgcn_mfma_f32_16x16x32_bf16(fa[cb][i][1], fb[cb][j][0], acc[i][j], 0, 0, 0);
            }
    }
#undef LOADC

    // stage into LDS: modes 0/1/3 as [m][n]; mode 2 as [n][m]
    #pragma unroll
    for (int i = 0; i < 2; ++i)
        #pragma unroll
        for (int j = 0; j < 2; ++j) {
            const int nl_ = (wv >> 1) * 32 + j * 16 + lr;
            const float bv = bias[N0 + nl_];
            #pragma unroll
            for (int r = 0; r < 4; ++r) {
                const int ml_ = (wv & 1) * 32 + i * 16 + lq * 4 + r;
                float v = acc[i][j][r] + bv;
                if (mode <= 1) v = __builtin_amdgcn_exp2f(SCALE2 * v);
                if (mode == 2) Ls[nl_][ml_] = v;
                else Ls[ml_][nl_] = v;
            }
        }
    __syncthreads();

    const int bh_i = (M0 >> 9) * NH + (N0 >> 6);
    const int tloc = M0 & 511;
    const int row = tid >> 2, c0 = (tid & 3) * 16;
    if (mode <= 1) {
        float* dst = (mode ? ekR : eq) + (size_t)bh_i * 32768 + (size_t)(tloc + row) * 64;
        #pragma unroll
        for (int c = 0; c < 4; ++c)
            *(float4*)&dst[c0 + 4 * c] = *(float4*)&Ls[row][c0 + 4 * c];
    } else if (mode == 2) {
        unsigned short* dst = KhT + ((size_t)bh_i * 64 + row) * 512 + tloc + c0;
        union { short8 v; unsigned short u[8]; } o0, o1;
        #pragma unroll
        for (int i = 0; i < 8; ++i) {
            o0.u[i] = bf16u(Ls[row][c0 + i]);
            o1.u[i] = bf16u(Ls[row][c0 + 8 + i]);
        }
        *(short8*)dst = o0.v;
        *(short8*)(dst + 8) = o1.v;
    } else {
        float* dst = out + (size_t)(M0 + row) * 512 + N0;
        #pragma unroll
        for (int c = 0; c < 4; ++c)
            *(float4*)&dst[c0 + 4 * c] = *(float4*)&Ls[row][c0 + 4 * c];
    }
}

// ===== attention core v5: XCD-swizzled, vectorized ekR, scalar-load eq =====
// acc[t] = sum_e va[e] * rcp(1 + eq[t][e]*ek[s][e]);  p = softmax(-2*acc)
// out[t,d] = sum_s p[t,s]*K[s,d]  via bf16 MFMA
__global__ __launch_bounds__(512, 4) void attn_v5(
    const float* __restrict__ eq, const float* __restrict__ ekR,
    const unsigned short* __restrict__ KhT, const float* __restrict__ va_h,
    unsigned short* __restrict__ mh, unsigned short* __restrict__ ml)
{
    __shared__ __hip_bfloat16 pA[16][520];
    __shared__ float wsum[8][8];

    const int tid = threadIdx.x;
    const int w = tid >> 6, l = tid & 63;
    // swizzle: bh in low 4 bits -> all same-(b,h) blocks share an XCD (id%8 const)
    const int bh_i = blockIdx.x & 15;
    const int t0 = (blockIdx.x >> 4) * 8;
    const int b = bh_i >> 3, h = bh_i & 7;

    const float* eq_p = eq + (size_t)bh_i * 32768 + (size_t)t0 * 64;   // uniform
    const float* ek_p = ekR + (size_t)bh_i * 32768 + (size_t)tid * 64; // per-thread s
    const float* va_p = va_h + h * 64;                                  // uniform

    float acc[8];
    #pragma unroll
    for (int t = 0; t < 8; ++t) acc[t] = 0.f;

    #pragma unroll
    for (int e0 = 0; e0 < 64; e0 += 16) {
        float4 ekv[4];
        #pragma unroll
        for (int q = 0; q < 4; ++q) ekv[q] = *(const float4*)&ek_p[e0 + 4 * q];
        float4 nv[4];
        #pragma unroll
        for (int q = 0; q < 4; ++q) nv[q] = *(const float4*)&va_p[e0 + 4 * q];  // uniform -> s_load
        #pragma unroll
        for (int t = 0; t < 8; ++t) {
            float a = acc[t];
            #pragma unroll
            for (int q = 0; q < 4; ++q) {
                float4 e4 = *(const float4*)&eq_p[t * 64 + e0 + 4 * q];  // uniform -> s_load
                a = fmaf(nv[q].x, __builtin_amdgcn_rcpf(fmaf(e4.x, ekv[q].x, 1.0f)), a);
                a = fmaf(nv[q].y, __builtin_amdgcn_rcpf(fmaf(e4.y, ekv[q].y, 1.0f)), a);
                a = fmaf(nv[q].z, __builtin_amdgcn_rcpf(fmaf(e4.z, ekv[q].z, 1.0f)), a);
                a = fmaf(nv[q].w, __builtin_amdgcn_rcpf(fmaf(e4.w, ekv[q].w, 1.0f)), a);
            }
            acc[t] = a;
        }
    }

    // softmax over s (score = -2*acc, bounded -> no max-subtract)
    float ev[8];
    #pragma unroll
    for (int t = 0; t < 8; ++t) {
        float s = __builtin_amdgcn_exp2f(acc[t] * N2LOG2E);
        ev[t] = s;
        #pragma unroll
        for (int off = 32; off > 0; off >>= 1) s += __shfl_xor(s, off, 64);
        if (l == 0) wsum[t][w] = s;
    }
    __syncthreads();
    #pragma unroll
    for (int t = 0; t < 8; ++t) {
        float4 s0 = *(float4*)&wsum[t][0];
        float4 s1 = *(float4*)&wsum[t][4];
        float inv = 1.0f / (((s0.x + s0.y) + (s0.z + s0.w)) + ((s1.x + s1.y) + (s1.z + s1.w)));
        pA[t][tid] = __hip_bfloat16(ev[t] * inv);
    }
    {   // zero-pad rows 8..15 for the MFMA A-read
        short8 z = {0, 0, 0, 0, 0, 0, 0, 0};
        *(short8*)&pA[8 + w][l * 8] = z;
    }
    __syncthreads();

    // P(16x512, rows 8..15 zero) @ K(512x64); wave w<4 owns d in [16w,16w+16)
    if (w < 4) {
        const unsigned short* kp = KhT + (size_t)bh_i * 32768
                                   + ((size_t)(w * 16 + (l & 15))) * 512 + (l >> 4) * 8;
        const __hip_bfloat16* ap = &pA[l & 15][(l >> 4) * 8];
        floatx4 oacc = {0.f, 0.f, 0.f, 0.f};
        #pragma unroll
        for (int kt = 0; kt < 16; ++kt) {
            short8 af = *(const short8*)(ap + kt * 32);
            short8 bf = *(const short8*)(kp + kt * 32);
            oacc = __builtin_amdgcn_mfma_f32_16x16x32_bf16(af, bf, oacc, 0, 0, 0);
        }
        const int lq = l >> 4;
        if (lq < 2) {
            const int kcol = h * 64 + w * 16 + (l & 15);
            #pragma unroll
            for (int r = 0; r < 4; ++r) {
                const size_t idx = (size_t)(b * 512 + t0 + lq * 4 + r) * 512 + kcol;
                unsigned short hi, lo;
                split2(oacc[r], hi, lo);
                mh[idx] = hi;
                ml[idx] = lo;
            }
        }
    }
}

extern "C" void kernel_launch(void* const* d_in, const int* in_sizes, int n_in,
                              void* d_out, int out_size, void* d_ws, size_t ws_size,
                              hipStream_t stream) {
    (void)in_sizes; (void)n_in; (void)out_size; (void)ws_size;
    const float* query = (const float*)d_in[0];
    const float* key   = (const float*)d_in[1];
    // d_in[2] (value), d_in[7] (Wv), d_in[8] (bv): dead in the reference
    const float* Wq   = (const float*)d_in[3];
    const float* bq   = (const float*)d_in[4];
    const float* Wk   = (const float*)d_in[5];
    const float* bk   = (const float*)d_in[6];
    const float* Wq_h = (const float*)d_in[9];
    const float* Wk_h = (const float*)d_in[10];
    const float* va_h = (const float*)d_in[11];
    const float* b_h  = (const float*)d_in[12];
    const float* Wo   = (const float*)d_in[13];
    const float* bo   = (const float*)d_in[14];
    float* out = (float*)d_out;

    float* ws = (float*)d_ws;
    float* eqb  = ws;                    // 524288 f   [bh][t][e]
    float* ekRb = eqb + 524288;          // 524288 f   [bh][s][e]
    float* bqe  = ekRb + 524288;         // 512
    float* bke  = bqe + 512;             // 512
    unsigned short* u = (unsigned short*)(bke + 512);
    unsigned short* qkh = u;   u += 1048576;   // query|key split hi
    unsigned short* qkl = u;   u += 1048576;   // query|key split lo
    unsigned short* WqeTh = u; u += 262144;
    unsigned short* WqeTl = u; u += 262144;
    unsigned short* WkeTh = u; u += 262144;
    unsigned short* WkeTl = u; u += 262144;
    unsigned short* WkTh = u;  u += 262144;
    unsigned short* WkTl = u;  u += 262144;
    unsigned short* WoTh = u;  u += 262144;
    unsigned short* WoTl = u;  u += 262144;
    unsigned short* KhTb = u;  u += 524288;    // [bh][d][s] bf16
    unsigned short* mh = qkh;                  // merged aliases query half
    unsigned short* ml = qkl;

    prep_all<<<dim3(513), 256, 0, stream>>>(
        Wq, Wk, Wo, Wq_h, Wk_h, b_h, bq, bk, query, key,
        WkTh, WkTl, WoTh, WoTl, WqeTh, WqeTl, WkeTh, WkeTl, bqe, bke, qkh, qkl);

    // eq / ekR / KhT (modes 0,1,2)
    gemm_bf16<<<dim3(8, 16, 3), 256, 0, stream>>>(
        qkh, qkl, mh, ml,
        WqeTh, WqeTl, WkeTh, WkeTl, WkTh, WkTl, WoTh, WoTl,
        bqe, bke, bk, bo, eqb, ekRb, KhTb, out, 0);

    // scores -> softmax -> P@K -> merged (pre-split bf16)
    attn_v5<<<dim3(1024), 512, 0, stream>>>(eqb, ekRb, KhTb, va_h, mh, ml);

    // out = merged@Wo + bo (mode 3)
    gemm_bf16<<<dim3(8, 16, 1), 256, 0, stream>>>(
        qkh, qkl, mh, ml,
        WqeTh, WqeTl, WkeTh, WkeTl, WkTh, WkTl, WoTh, WoTl,
        bqe, bke, bk, bo, eqb, ekRb, KhTb, out, 3);
}